// Round 23
// baseline (357.094 us; speedup 1.0000x reference)
//
#include <hip/hip_runtime.h>
#include <cstddef>
#include <cstdint>

#define ALPHA 0.9f
#define BETA  0.8f

// ---------------- sizes ----------------
// conv1: 32x3x8x8 s4 -> [256,32,55,55]   (MFMA bf16x4, fused conversion via v_cvt_pk_bf16_f32)
// conv2: 64x32x4x4 s2 -> [256,64,26,26]  (MFMA bf16x3, 2-batch x 48 pos x 64 cout wave tile)
// conv3: 64x64x3x3 s1 -> [256,64,24,24]  (MFMA bf16x3, cin-split two-phase LDS slab)
// fc1:   split-K MFMA bf16x3, wave = 32 samples x 32 outs (acc[2][2])
// Epilogues use paired v_cvt_pk_bf16_f32 (bit-identical to f2bf RNE).
// base k-index is PERMUTED: feat k = pos*64+cout (w1 planes permuted to match);
// history tail [36864,36954) identity. KP = 36960 (= 33*35*32)
#define FEAT   36864
#define HIST   90
#define K1     36954
#define KP     36960

typedef __attribute__((ext_vector_type(8))) short short8;
typedef __attribute__((ext_vector_type(4))) float f32x4;
typedef __attribute__((ext_vector_type(2))) int int2v;

__device__ __forceinline__ unsigned short f2bf(float x) {
  unsigned u = __float_as_uint(x);
  return (unsigned short)((u + 0x7FFFu + ((u >> 16) & 1u)) >> 16);
}
__device__ __forceinline__ float bf2f(unsigned short h) {
  return __uint_as_float(((unsigned)h) << 16);
}

// packed hi/lo split of 8 fp32 via v_cvt_pk_bf16_f32 (RNE): ~6 VALU per 2 elems
__device__ __forceinline__ short8 cvt_hi_lo8(const float* __restrict__ v, short8& lov) {
  union { unsigned u[4]; short8 s; } H, L;
#pragma unroll
  for (int q = 0; q < 4; ++q) {
    unsigned h, l;
    asm("v_cvt_pk_bf16_f32 %0, %1, %2" : "=v"(h) : "v"(v[2 * q]), "v"(v[2 * q + 1]));
    float h0 = __uint_as_float(h << 16);
    float h1 = __uint_as_float(h & 0xffff0000u);
    asm("v_cvt_pk_bf16_f32 %0, %1, %2" : "=v"(l) : "v"(v[2 * q] - h0), "v"(v[2 * q + 1] - h1));
    H.u[q] = h; L.u[q] = l;
  }
  lov = L.s;
  return H.s;
}

// paired epilogue split: v0,v1 -> hi0,hi1,lo0,lo1 (bit-identical to f2bf path)
__device__ __forceinline__ void cvt2(float v0, float v1, unsigned& hp, unsigned& lp) {
  asm("v_cvt_pk_bf16_f32 %0, %1, %2" : "=v"(hp) : "v"(v0), "v"(v1));
  float h0 = __uint_as_float(hp << 16);
  float h1 = __uint_as_float(hp & 0xffff0000u);
  asm("v_cvt_pk_bf16_f32 %0, %1, %2" : "=v"(lp) : "v"(v0 - h0), "v"(v1 - h1));
}

// ---- conv1 weights [32][3][8][8] -> [pair=c*8+kh][cout][kw] bf16 hi/lo ----
__global__ __launch_bounds__(256) void convert_w1c(const float* __restrict__ w,
    unsigned short* __restrict__ hi, unsigned short* __restrict__ lo)
{
  int i = blockIdx.x * 256 + threadIdx.x;
  if (i >= 6144) return;
  int kw = i & 7, rest = i >> 3;
  int cout = rest & 31, pair = rest >> 5;
  int c = pair >> 3, kh = pair & 7;
  float x = w[((cout * 3 + c) * 8 + kh) * 8 + kw];
  unsigned short h = f2bf(x);
  hi[i] = h; lo[i] = f2bf(x - bf2f(h));
}

// ---- conv1 MFMA bf16x4, fused fp32->bf16 hi/lo via packed cvt ----
__global__ __launch_bounds__(256) void conv1_mfma(const float* __restrict__ state,
    const unsigned short* __restrict__ whi, const unsigned short* __restrict__ wlo,
    const float* __restrict__ bias, unsigned short* __restrict__ ohi,
    unsigned short* __restrict__ olo, int batch0)
{
  int wv = threadIdx.x >> 6, lane = threadIdx.x & 63;
  int b = blockIdx.y;             // local batch 0..127
  int l15 = lane & 15, kg = lane >> 4;
  int posbase = blockIdx.x * 192 + wv * 48;
  int rowb[3];
#pragma unroll
  for (int i = 0; i < 3; ++i) {
    int pos = posbase + i * 16 + l15;
    int cp = pos > 3024 ? 3024 : pos;
    int y = cp / 55, x = cp % 55;
    rowb[i] = (y * 4) * 224 + x * 4;
  }
  const float* ip = state + (size_t)(batch0 + b) * 150528;
  f32x4 acc[3][2];
#pragma unroll
  for (int i = 0; i < 3; ++i) {
    acc[i][0] = (f32x4){0.f, 0.f, 0.f, 0.f};
    acc[i][1] = (f32x4){0.f, 0.f, 0.f, 0.f};
  }
#pragma unroll 2
  for (int s = 0; s < 6; ++s) {
    int pair = s * 4 + kg;
    int c = pair >> 3, kh = pair & 7;
    int aoff = c * 50176 + kh * 224;
    short8 Ah[3], Al[3], Bh[2], Bl[2];
#pragma unroll
    for (int i = 0; i < 3; ++i) {
      const float* p = ip + aoff + rowb[i];
      const float4 f0 = *(const float4*)p;
      const float4 f1 = *(const float4*)(p + 4);
      float v[8] = {f0.x, f0.y, f0.z, f0.w, f1.x, f1.y, f1.z, f1.w};
      Ah[i] = cvt_hi_lo8(v, Al[i]);
    }
    int wb = (pair * 32 + l15) * 8;
#pragma unroll
    for (int nt = 0; nt < 2; ++nt) {
      Bh[nt] = *(const short8*)(whi + wb + nt * 128);
      Bl[nt] = *(const short8*)(wlo + wb + nt * 128);
    }
#pragma unroll
    for (int i = 0; i < 3; ++i)
#pragma unroll
      for (int nt = 0; nt < 2; ++nt) {
        acc[i][nt] = __builtin_amdgcn_mfma_f32_16x16x32_bf16(Ah[i], Bh[nt], acc[i][nt], 0, 0, 0);
        acc[i][nt] = __builtin_amdgcn_mfma_f32_16x16x32_bf16(Ah[i], Bl[nt], acc[i][nt], 0, 0, 0);
        acc[i][nt] = __builtin_amdgcn_mfma_f32_16x16x32_bf16(Al[i], Bh[nt], acc[i][nt], 0, 0, 0);
        acc[i][nt] = __builtin_amdgcn_mfma_f32_16x16x32_bf16(Al[i], Bl[nt], acc[i][nt], 0, 0, 0);
      }
  }
  float bv0 = bias[l15], bv1 = bias[16 + l15];
#pragma unroll
  for (int i = 0; i < 3; ++i) {
#pragma unroll
    for (int r = 0; r < 4; ++r) {
      int pos = posbase + i * 16 + kg * 4 + r;
      if (pos < 3025) {
        size_t o = ((size_t)b * 3025 + pos) * 32 + l15;
        float v0 = acc[i][0][r] + bv0; v0 = v0 > 0.f ? v0 : 0.f;
        float v1 = acc[i][1][r] + bv1; v1 = v1 > 0.f ? v1 : 0.f;
        unsigned hp, lp;
        cvt2(v0, v1, hp, lp);
        ohi[o]      = (unsigned short)(hp & 0xffff);
        ohi[o + 16] = (unsigned short)(hp >> 16);
        olo[o]      = (unsigned short)(lp & 0xffff);
        olo[o + 16] = (unsigned short)(lp >> 16);
      }
    }
  }
}

// ---- conv2 weights [64][32][4][4] fp32 -> [tap][cout][cin] bf16 hi/lo ----
__global__ __launch_bounds__(256) void convert_w2(const float* __restrict__ w,
    unsigned short* __restrict__ hi, unsigned short* __restrict__ lo)
{
  int i = blockIdx.x * 256 + threadIdx.x;
  if (i >= 16 * 64 * 32) return;
  int tap = i >> 11, rem = i & 2047;
  int co = rem >> 5, ci = rem & 31;
  float x = w[co * 512 + ci * 16 + tap];
  unsigned short h = f2bf(x);
  hi[i] = h; lo[i] = f2bf(x - bf2f(h));
}

// ---- conv2 MFMA bf16x3: wave = 2 batches x 48 pos x 64 cout (unchanged) ----
__global__ __launch_bounds__(256) void conv2_mfma(const unsigned short* __restrict__ xhi,
    const unsigned short* __restrict__ xlo, const unsigned short* __restrict__ whi,
    const unsigned short* __restrict__ wlo, const float* __restrict__ bias,
    unsigned short* __restrict__ ohi, unsigned short* __restrict__ olo, int batch0)
{
  int wv = threadIdx.x >> 6, lane = threadIdx.x & 63;
  int b0 = blockIdx.y * 2;            // local batch pair
  int l15 = lane & 15, kg = lane >> 4;
  int posbase = blockIdx.x * 192 + wv * 48;
  int pv[3];
#pragma unroll
  for (int i = 0; i < 3; ++i) {
    int pos = posbase + i * 16 + l15;
    int cp = pos > 675 ? 675 : pos;
    int y = cp / 26, x = cp % 26;
    pv[i] = (2 * y) * 55 + 2 * x;     // input base position index
  }
  size_t ibase0 = (size_t)b0 * 96800;       // 3025*32
  size_t ibase1 = ibase0 + 96800;
  int ibn[4];
#pragma unroll
  for (int nt = 0; nt < 4; ++nt) ibn[nt] = (nt * 16 + l15) * 32 + kg * 8;
  f32x4 acc[2][3][4];
#pragma unroll
  for (int bb = 0; bb < 2; ++bb)
#pragma unroll
    for (int i = 0; i < 3; ++i)
#pragma unroll
      for (int nt = 0; nt < 4; ++nt) acc[bb][i][nt] = (f32x4){0.f, 0.f, 0.f, 0.f};

#pragma unroll 2
  for (int tap = 0; tap < 16; ++tap) {
    int kh = tap >> 2, kw = tap & 3;
    int wb = tap * 2048;
    short8 A0h[3], A0l[3], A1h[3], A1l[3], Bh[4], Bl[4];
#pragma unroll
    for (int i = 0; i < 3; ++i) {
      int ia = (pv[i] + kh * 55 + kw) * 32 + kg * 8;
      A0h[i] = *(const short8*)(xhi + ibase0 + ia);
      A0l[i] = *(const short8*)(xlo + ibase0 + ia);
      A1h[i] = *(const short8*)(xhi + ibase1 + ia);
      A1l[i] = *(const short8*)(xlo + ibase1 + ia);
    }
#pragma unroll
    for (int nt = 0; nt < 4; ++nt) {
      Bh[nt] = *(const short8*)(whi + wb + ibn[nt]);
      Bl[nt] = *(const short8*)(wlo + wb + ibn[nt]);
    }
#pragma unroll
    for (int i = 0; i < 3; ++i)
#pragma unroll
      for (int nt = 0; nt < 4; ++nt) {
        acc[0][i][nt] = __builtin_amdgcn_mfma_f32_16x16x32_bf16(A0h[i], Bh[nt], acc[0][i][nt], 0, 0, 0);
        acc[0][i][nt] = __builtin_amdgcn_mfma_f32_16x16x32_bf16(A0h[i], Bl[nt], acc[0][i][nt], 0, 0, 0);
        acc[0][i][nt] = __builtin_amdgcn_mfma_f32_16x16x32_bf16(A0l[i], Bh[nt], acc[0][i][nt], 0, 0, 0);
        acc[1][i][nt] = __builtin_amdgcn_mfma_f32_16x16x32_bf16(A1h[i], Bh[nt], acc[1][i][nt], 0, 0, 0);
        acc[1][i][nt] = __builtin_amdgcn_mfma_f32_16x16x32_bf16(A1h[i], Bl[nt], acc[1][i][nt], 0, 0, 0);
        acc[1][i][nt] = __builtin_amdgcn_mfma_f32_16x16x32_bf16(A1l[i], Bh[nt], acc[1][i][nt], 0, 0, 0);
      }
  }
  float bv[4];
#pragma unroll
  for (int nt = 0; nt < 4; ++nt) bv[nt] = bias[nt * 16 + l15];
#pragma unroll
  for (int bb = 0; bb < 2; ++bb) {
    size_t obase = (size_t)(batch0 + b0 + bb) * 676;
#pragma unroll
    for (int i = 0; i < 3; ++i) {
#pragma unroll
      for (int r = 0; r < 4; ++r) {
        int pos = posbase + i * 16 + kg * 4 + r;
        if (pos < 676) {
          size_t o = (obase + pos) * 64 + l15;
#pragma unroll
          for (int np = 0; np < 2; ++np) {
            float v0 = acc[bb][i][2 * np][r] + bv[2 * np];         v0 = v0 > 0.f ? v0 : 0.f;
            float v1 = acc[bb][i][2 * np + 1][r] + bv[2 * np + 1]; v1 = v1 > 0.f ? v1 : 0.f;
            unsigned hp, lp;
            cvt2(v0, v1, hp, lp);
            ohi[o + (2 * np) * 16]     = (unsigned short)(hp & 0xffff);
            ohi[o + (2 * np + 1) * 16] = (unsigned short)(hp >> 16);
            olo[o + (2 * np) * 16]     = (unsigned short)(lp & 0xffff);
            olo[o + (2 * np + 1) * 16] = (unsigned short)(lp >> 16);
          }
        }
      }
    }
  }
}

// ---- conv3 weights [cout][cin][3][3] fp32 -> [tap][cout][cin] bf16 hi/lo ----
__global__ __launch_bounds__(256) void convert_w3(const float* __restrict__ w,
    unsigned short* __restrict__ hi, unsigned short* __restrict__ lo)
{
  int i = blockIdx.x * 256 + threadIdx.x;
  if (i >= 9 * 64 * 64) return;
  int tap = i >> 12, rem = i & 4095;
  int cout = rem >> 6, cin = rem & 63;
  float x = w[cout * 576 + cin * 9 + tap];
  unsigned short h = f2bf(x);
  hi[i] = h; lo[i] = f2bf(x - bf2f(h));
}

// ---- conv3 MFMA bf16x3: 4 waves/block, 192 pos, 10-row cin-split slab (unchanged) ----
__global__ __launch_bounds__(256) void conv3_mfma(const unsigned short* __restrict__ xhi,
    const unsigned short* __restrict__ xlo, const unsigned short* __restrict__ whi,
    const unsigned short* __restrict__ wlo, const float* __restrict__ bias,
    unsigned short* __restrict__ bhi, unsigned short* __restrict__ blo)
{
  __shared__ unsigned short slabh[260 * 40];   // 20800 B
  __shared__ unsigned short slabl[260 * 40];
  int t = threadIdx.x;
  int wv = t >> 6, lane = t & 63;
  int pchunk = blockIdx.x;    // 0..2 (8 output rows each)
  int b = blockIdx.y;         // 0..255
  const unsigned short* gh = xhi + (size_t)b * 43264 + pchunk * 13312;  // 8*26*64
  const unsigned short* gl = xlo + (size_t)b * 43264 + pchunk * 13312;
  int l15 = lane & 15, kg = lane >> 4;
  int posbase = pchunk * 192 + wv * 48;
  int lr[3], lx[3];
#pragma unroll
  for (int i = 0; i < 3; ++i) {
    int pos = posbase + i * 16 + l15;
    int y = pos / 24, x = pos % 24;
    lr[i] = y - pchunk * 8;      // 0..7
    lx[i] = x;
  }
  int ibn[4];
#pragma unroll
  for (int nt = 0; nt < 4; ++nt) ibn[nt] = (nt * 16 + l15) * 64 + kg * 8;
  f32x4 acc[3][4];
#pragma unroll
  for (int i = 0; i < 3; ++i)
#pragma unroll
    for (int nt = 0; nt < 4; ++nt) acc[i][nt] = (f32x4){0.f, 0.f, 0.f, 0.f};

#pragma unroll 1
  for (int ks = 0; ks < 2; ++ks) {
    if (ks) __syncthreads();
    for (int e = t; e < 1040; e += 256) {     // 260 pos x 4 chunks of 8 shorts
      int p = e >> 2, s = e & 3;
      *(short8*)(slabh + p * 40 + s * 8) = *(const short8*)(gh + p * 64 + ks * 32 + s * 8);
      *(short8*)(slabl + p * 40 + s * 8) = *(const short8*)(gl + p * 64 + ks * 32 + s * 8);
    }
    __syncthreads();
    int ko = ks * 32;
#pragma unroll 3
    for (int tap = 0; tap < 9; ++tap) {
      int kh = tap / 3, kw = tap % 3;
      int wboff = tap * 4096 + ko;
      short8 Ah[3], Al[3], Bh[4], Bl[4];
#pragma unroll
      for (int i = 0; i < 3; ++i) {
        int p = (lr[i] + kh) * 26 + lx[i] + kw;    // 0..259
        int d = p * 40 + kg * 8;
        Ah[i] = *(const short8*)(slabh + d);
        Al[i] = *(const short8*)(slabl + d);
      }
#pragma unroll
      for (int nt = 0; nt < 4; ++nt) {
        Bh[nt] = *(const short8*)(whi + wboff + ibn[nt]);
        Bl[nt] = *(const short8*)(wlo + wboff + ibn[nt]);
      }
#pragma unroll
      for (int i = 0; i < 3; ++i)
#pragma unroll
        for (int nt = 0; nt < 4; ++nt) {
          acc[i][nt] = __builtin_amdgcn_mfma_f32_16x16x32_bf16(Ah[i], Bh[nt], acc[i][nt], 0, 0, 0);
          acc[i][nt] = __builtin_amdgcn_mfma_f32_16x16x32_bf16(Ah[i], Bl[nt], acc[i][nt], 0, 0, 0);
          acc[i][nt] = __builtin_amdgcn_mfma_f32_16x16x32_bf16(Al[i], Bh[nt], acc[i][nt], 0, 0, 0);
        }
    }
  }
  float bv[4];
#pragma unroll
  for (int nt = 0; nt < 4; ++nt) bv[nt] = bias[nt * 16 + l15];
  size_t ob = (size_t)b * KP;
#pragma unroll
  for (int i = 0; i < 3; ++i) {
#pragma unroll
    for (int r = 0; r < 4; ++r) {
      int pos = posbase + i * 16 + kg * 4 + r;
      size_t o = ob + (size_t)pos * 64 + l15;
#pragma unroll
      for (int np = 0; np < 2; ++np) {
        float v0 = acc[i][2 * np][r] + bv[2 * np];         v0 = v0 > 0.f ? v0 : 0.f;
        float v1 = acc[i][2 * np + 1][r] + bv[2 * np + 1]; v1 = v1 > 0.f ? v1 : 0.f;
        unsigned hp, lp;
        cvt2(v0, v1, hp, lp);
        bhi[o + (2 * np) * 16]     = (unsigned short)(hp & 0xffff);
        bhi[o + (2 * np + 1) * 16] = (unsigned short)(hp >> 16);
        blo[o + (2 * np) * 16]     = (unsigned short)(lp & 0xffff);
        blo[o + (2 * np + 1) * 16] = (unsigned short)(lp >> 16);
      }
    }
  }
}

// ---- fill history tail + zero pad of base planes: k in [36864, 36960), identity ----
__global__ __launch_bounds__(128) void fill_hist(const float* __restrict__ hist,
    unsigned short* __restrict__ bhi, unsigned short* __restrict__ blo)
{
  int b = blockIdx.x, t = threadIdx.x;
  int k = FEAT + t;
  if (k >= KP) return;
  float x = (k < K1) ? hist[b * HIST + t] : 0.f;
  unsigned short h = f2bf(x);
  size_t o = (size_t)b * KP + k;
  bhi[o] = h; blo[o] = f2bf(x - bf2f(h));
}

// ---- fc1 weights feat part, PERMUTED to pos-major: dst[o][pos*64+c] = w[o][c*576+pos] ----
__global__ __launch_bounds__(256) void convert_w1(const float* __restrict__ w,
    unsigned short* __restrict__ hi, unsigned short* __restrict__ lo)
{
  __shared__ float tl[64][65];
  int o = blockIdx.y;
  int p0 = blockIdx.x * 64;
  int t = threadIdx.x;
  const float* src = w + (size_t)o * K1;
  for (int e = t; e < 4096; e += 256) {
    int c = e >> 6, p = e & 63;
    tl[p][c] = src[c * 576 + p0 + p];
  }
  __syncthreads();
  size_t dbase = (size_t)o * KP;
  for (int e = t; e < 4096; e += 256) {
    int p = e >> 6, c = e & 63;
    float x = tl[p][c];
    unsigned short h = f2bf(x);
    size_t d = dbase + (size_t)(p0 + p) * 64 + c;
    hi[d] = h; lo[d] = f2bf(x - bf2f(h));
  }
}

// ---- fc1 weights history tail [36864, 36960), identity mapping ----
__global__ __launch_bounds__(128) void convert_w1_tail(const float* __restrict__ w,
    unsigned short* __restrict__ hi, unsigned short* __restrict__ lo)
{
  int o = blockIdx.x, t = threadIdx.x;
  int k = FEAT + t;
  if (k >= KP) return;
  float x = (k < K1) ? w[(size_t)o * K1 + k] : 0.f;
  unsigned short h = f2bf(x);
  size_t p = (size_t)o * KP + k;
  hi[p] = h; lo[p] = f2bf(x - bf2f(h));
}

// ---------------- fc2 weight transpose: [256][128] -> [128][256] ----------------
__global__ __launch_bounds__(256) void transpose_fc2(const float* __restrict__ w,
                                                     float* __restrict__ wT)
{
  int idx = blockIdx.x * 256 + threadIdx.x;
  if (idx < 128 * 256) {
    int i = idx >> 8, j = idx & 255;
    wT[idx] = w[j * 128 + i];
  }
}

// ---- fc1 MFMA bf16x3 split-K v2: wave = 32 samples x 32 outs (acc[2][2]) ----
// grid (8, 33): job = bx*4+wv in [0,32); mt2 = job>>2 (8 sample tiles of 32),
// nt2 = job&3 (4 out tiles of 32). Per k-step: 8 loads feed 12 MFMAs.
__global__ __launch_bounds__(256) void fc1_mfma(const unsigned short* __restrict__ bhi,
    const unsigned short* __restrict__ blo, const unsigned short* __restrict__ whi,
    const unsigned short* __restrict__ wlo, float* __restrict__ part)
{
  int w = threadIdx.x >> 6, lane = threadIdx.x & 63;
  int job = blockIdx.x * 4 + w;        // 0..31
  int mt2 = job >> 2, nt2 = job & 3;
  int ks = blockIdx.y;                 // 0..32
  int k0 = ks * 35 * 32;
  int l15 = lane & 15, kg = lane >> 4;
  int s0 = mt2 * 32 + l15;
  int o0 = nt2 * 32 + l15;
  const unsigned short* pa0h = bhi + (size_t)s0 * KP + k0 + kg * 8;
  const unsigned short* pa1h = pa0h + (size_t)16 * KP;
  const unsigned short* pa0l = blo + (size_t)s0 * KP + k0 + kg * 8;
  const unsigned short* pa1l = pa0l + (size_t)16 * KP;
  const unsigned short* pb0h = whi + (size_t)o0 * KP + k0 + kg * 8;
  const unsigned short* pb1h = pb0h + (size_t)16 * KP;
  const unsigned short* pb0l = wlo + (size_t)o0 * KP + k0 + kg * 8;
  const unsigned short* pb1l = pb0l + (size_t)16 * KP;
  f32x4 acc[2][2];
  acc[0][0] = (f32x4){0.f, 0.f, 0.f, 0.f};
  acc[0][1] = (f32x4){0.f, 0.f, 0.f, 0.f};
  acc[1][0] = (f32x4){0.f, 0.f, 0.f, 0.f};
  acc[1][1] = (f32x4){0.f, 0.f, 0.f, 0.f};
#pragma unroll 1
  for (int i = 0; i < 35; ++i) {
    short8 a0h = *(const short8*)pa0h;
    short8 a1h = *(const short8*)pa1h;
    short8 a0l = *(const short8*)pa0l;
    short8 a1l = *(const short8*)pa1l;
    short8 b0h = *(const short8*)pb0h;
    short8 b1h = *(const short8*)pb1h;
    short8 b0l = *(const short8*)pb0l;
    short8 b1l = *(const short8*)pb1l;
    acc[0][0] = __builtin_amdgcn_mfma_f32_16x16x32_bf16(a0h, b0h, acc[0][0], 0, 0, 0);
    acc[0][1] = __builtin_amdgcn_mfma_f32_16x16x32_bf16(a0h, b1h, acc[0][1], 0, 0, 0);
    acc[1][0] = __builtin_amdgcn_mfma_f32_16x16x32_bf16(a1h, b0h, acc[1][0], 0, 0, 0);
    acc[1][1] = __builtin_amdgcn_mfma_f32_16x16x32_bf16(a1h, b1h, acc[1][1], 0, 0, 0);
    acc[0][0] = __builtin_amdgcn_mfma_f32_16x16x32_bf16(a0h, b0l, acc[0][0], 0, 0, 0);
    acc[0][1] = __builtin_amdgcn_mfma_f32_16x16x32_bf16(a0h, b1l, acc[0][1], 0, 0, 0);
    acc[1][0] = __builtin_amdgcn_mfma_f32_16x16x32_bf16(a1h, b0l, acc[1][0], 0, 0, 0);
    acc[1][1] = __builtin_amdgcn_mfma_f32_16x16x32_bf16(a1h, b1l, acc[1][1], 0, 0, 0);
    acc[0][0] = __builtin_amdgcn_mfma_f32_16x16x32_bf16(a0l, b0h, acc[0][0], 0, 0, 0);
    acc[0][1] = __builtin_amdgcn_mfma_f32_16x16x32_bf16(a0l, b1h, acc[0][1], 0, 0, 0);
    acc[1][0] = __builtin_amdgcn_mfma_f32_16x16x32_bf16(a1l, b0h, acc[1][0], 0, 0, 0);
    acc[1][1] = __builtin_amdgcn_mfma_f32_16x16x32_bf16(a1l, b1h, acc[1][1], 0, 0, 0);
    pa0h += 32; pa1h += 32; pa0l += 32; pa1l += 32;
    pb0h += 32; pb1h += 32; pb0l += 32; pb1l += 32;
  }
  // partial layout: part[((ks*32 + job)*4 + mi*2 + ni)*256 + r*64 + lane]
  float* pp = part + ((size_t)ks * 32 + job) * 1024;
#pragma unroll
  for (int mi = 0; mi < 2; ++mi)
#pragma unroll
    for (int ni = 0; ni < 2; ++ni)
#pragma unroll
      for (int r = 0; r < 4; ++r)
        pp[(mi * 2 + ni) * 256 + r * 64 + lane] = acc[mi][ni][r];
}

// ---- fixed-order split-K reduce (matches fc1_mfma v2 layout) ----
__global__ __launch_bounds__(256) void fc1_reduce(const float* __restrict__ part,
                                                  float* __restrict__ h1)
{
  int i = blockIdx.x * 256 + threadIdx.x;
  if (i >= 32768) return;
  int s = i >> 7, o = i & 127;
  int mt2 = s >> 5, st = s & 31, mi = st >> 4, sr = st & 15;
  int nt2 = o >> 5, ot = o & 31, ni = ot >> 4, c = ot & 15;
  int job = mt2 * 4 + nt2;
  int off = (job * 4 + mi * 2 + ni) * 256 + (sr & 3) * 64 + ((sr >> 2) << 4) + c;
  float sum = 0.f;
#pragma unroll 1
  for (int ks = 0; ks < 33; ++ks) sum += part[(size_t)ks * 32768 + off];
  h1[i] = sum;
}

// ---------------- SNN simulation: branchless unrolled fc2 matvec ----------------
__global__ __launch_bounds__(256) void snn_ker(const float* __restrict__ h1,
    const float* __restrict__ b1, const float* __restrict__ w2T,
    const float* __restrict__ b2p, const float* __restrict__ w3,
    const float* __restrict__ b3p, float* __restrict__ out)
{
  int b = blockIdx.x, t = threadIdx.x;
  __shared__ float spk1l[128];
  __shared__ float part[4][9];
  float h1v = 0.f;
  if (t < 128) h1v = h1[b * 128 + t] + b1[t];
  float b2 = b2p[t];
  float w3r[9];
#pragma unroll
  for (int j = 0; j < 9; ++j) w3r[j] = w3[j * 256 + t];
  float mem1 = 0.f, syn1 = 0.f, mem2 = 0.f, syn2 = 0.f;
  float syn3[9], mem3[9], pot[9];
#pragma unroll
  for (int j = 0; j < 9; ++j) { syn3[j] = 0.f; mem3[j] = 0.f; pot[j] = 0.f; }

#pragma unroll 1
  for (int step = 0; step < 10; ++step) {
    if (t < 128) {
      syn1 = ALPHA * syn1 + h1v;
      mem1 = BETA * mem1 + syn1;
      float s = (mem1 > 1.0f) ? 1.f : 0.f;
      spk1l[t] = s;
      mem1 -= s;
    }
    __syncthreads();
    float h2 = b2;
#pragma unroll
    for (int i = 0; i < 128; ++i) {
      h2 += spk1l[i] * w2T[i * 256 + t];
    }
    syn2 = ALPHA * syn2 + h2;
    mem2 = BETA * mem2 + syn2;
    float s2 = (mem2 > 1.0f) ? 1.f : 0.f;
    mem2 -= s2;

    float v[9];
#pragma unroll
    for (int j = 0; j < 9; ++j) v[j] = s2 * w3r[j];
#pragma unroll
    for (int j = 0; j < 9; ++j) {
      v[j] += __shfl_down(v[j], 32);
      v[j] += __shfl_down(v[j], 16);
      v[j] += __shfl_down(v[j], 8);
      v[j] += __shfl_down(v[j], 4);
      v[j] += __shfl_down(v[j], 2);
      v[j] += __shfl_down(v[j], 1);
    }
    if ((t & 63) == 0) {
#pragma unroll
      for (int j = 0; j < 9; ++j) part[t >> 6][j] = v[j];
    }
    __syncthreads();
    if (t == 0) {
#pragma unroll
      for (int j = 0; j < 9; ++j) {
        float h3 = part[0][j] + part[1][j] + part[2][j] + part[3][j] + b3p[j];
        syn3[j] = ALPHA * syn3[j] + h3;
        mem3[j] = BETA * mem3[j] + syn3[j];
        pot[j] += mem3[j];
      }
    }
  }
  if (t == 0) {
#pragma unroll
    for (int j = 0; j < 9; ++j) out[b * 9 + j] = pot[j] / 10.0f;
  }
}

// ---------------- host ----------------
extern "C" void kernel_launch(void* const* d_in, const int* in_sizes, int n_in,
                              void* d_out, int out_size, void* d_ws, size_t ws_size,
                              hipStream_t stream)
{
  const float* state = (const float*)d_in[0];
  const float* hist  = (const float*)d_in[1];
  const float* c1w   = (const float*)d_in[2];
  const float* c1b   = (const float*)d_in[3];
  const float* c2w   = (const float*)d_in[4];
  const float* c2b   = (const float*)d_in[5];
  const float* c3w   = (const float*)d_in[6];
  const float* c3b   = (const float*)d_in[7];
  const float* f1w   = (const float*)d_in[8];
  const float* f1b   = (const float*)d_in[9];
  const float* f2w   = (const float*)d_in[10];
  const float* f2b   = (const float*)d_in[11];
  const float* f3w   = (const float*)d_in[12];
  const float* f3b   = (const float*)d_in[13];
  float* out = (float*)d_out;
  float* ws  = (float*)d_ws;

  // workspace (float offsets), peak 29,419,520 floats (117.7 MB):
  //   c1hi [0, 6,195,200) c1lo [6,195,200, 12,390,400)       (half-batch, reused per pass;
  //        region later reused as base_hi [0, 4,730,880) base_lo [4,730,880, 9,461,760))
  //   c2hi [12,390,400, 17,928,192) c2lo [17,928,192, 23,465,984)  (full batch)
  //   w1_hi [23,465,984, 25,831,424) w1_lo [25,831,424, 28,196,864)
  //   partb [28,196,864, 29,278,208)
  //   w1chi [29,278,208, 29,281,280) w1clo [29,281,280, 29,284,352)
  //   w2hi [29,284,352, 29,300,736) w2lo [29,300,736, 29,317,120)
  //   w3hi [29,317,120, 29,335,552) w3lo [29,335,552, 29,353,984)
  //   h1 [29,353,984, 29,386,752) wT2 [29,386,752, 29,419,520)
  unsigned short* c1hi    = (unsigned short*)(ws);
  unsigned short* c1lo    = (unsigned short*)(ws + 6195200);
  unsigned short* base_hi = (unsigned short*)(ws);
  unsigned short* base_lo = (unsigned short*)(ws + 4730880);
  unsigned short* c2hi    = (unsigned short*)(ws + 12390400);
  unsigned short* c2lo    = (unsigned short*)(ws + 17928192);
  unsigned short* w1_hi   = (unsigned short*)(ws + 23465984);
  unsigned short* w1_lo   = (unsigned short*)(ws + 25831424);
  float* partb    = ws + 28196864;
  unsigned short* w1chi   = (unsigned short*)(ws + 29278208);
  unsigned short* w1clo   = (unsigned short*)(ws + 29281280);
  unsigned short* w2_hi   = (unsigned short*)(ws + 29284352);
  unsigned short* w2_lo   = (unsigned short*)(ws + 29300736);
  unsigned short* w3_hi   = (unsigned short*)(ws + 29317120);
  unsigned short* w3_lo   = (unsigned short*)(ws + 29335552);
  float* h1buf    = ws + 29353984;
  float* wT2      = ws + 29386752;

  convert_w1c<<<dim3(24), 256, 0, stream>>>(c1w, w1chi, w1clo);
  convert_w2<<<dim3(128), 256, 0, stream>>>(c2w, w2_hi, w2_lo);
  convert_w3<<<dim3(144), 256, 0, stream>>>(c3w, w3_hi, w3_lo);
  // half-batch conv1 -> conv2 passes (conv1 reads fp32 state directly)
  for (int p = 0; p < 2; ++p) {
    conv1_mfma<<<dim3(16, 128), 256, 0, stream>>>(state, w1chi, w1clo, c1b,
                                                  c1hi, c1lo, p * 128);
    conv2_mfma<<<dim3(4, 64), 256, 0, stream>>>(c1hi, c1lo, w2_hi, w2_lo, c2b,
                                                c2hi, c2lo, p * 128);
  }
  // c1 dead -> region reused for base planes
  convert_w1<<<dim3(9, 128), 256, 0, stream>>>(f1w, w1_hi, w1_lo);
  convert_w1_tail<<<dim3(128), 128, 0, stream>>>(f1w, w1_hi, w1_lo);
  fill_hist<<<dim3(256), 128, 0, stream>>>(hist, base_hi, base_lo);
  conv3_mfma<<<dim3(3, 256), 256, 0, stream>>>(c2hi, c2lo, w3_hi, w3_lo, c3b,
                                               base_hi, base_lo);
  transpose_fc2<<<dim3(128), 256, 0, stream>>>(f2w, wT2);
  fc1_mfma<<<dim3(8, 33), 256, 0, stream>>>(base_hi, base_lo, w1_hi, w1_lo, partb);
  fc1_reduce<<<dim3(128), 256, 0, stream>>>(partb, h1buf);
  snn_ker<<<dim3(256), 256, 0, stream>>>(h1buf, f1b, wT2, f2b, f3w, f3b, out);
}

// Round 24
// 343.710 us; speedup vs baseline: 1.0389x; 1.0389x over previous
//
#include <hip/hip_runtime.h>
#include <cstddef>
#include <cstdint>

#define ALPHA 0.9f
#define BETA  0.8f

// ---------------- sizes ----------------
// conv1: 32x3x8x8 s4 -> [256,32,55,55]   (MFMA bf16x4, fused conversion via v_cvt_pk_bf16_f32)
// conv2: 64x32x4x4 s2 -> [256,64,26,26]  (MFMA bf16x3, 2-batch x 48 pos x 64 cout wave tile)
// conv3: 64x64x3x3 s1 -> [256,64,24,24]  (MFMA bf16x3, cin-split two-phase LDS slab)
// fc1:   split-K MFMA bf16x3, wave = 32 samples x 16 outs (round-22 config)
// Small weight conversions merged into one kernel (convert_small).
// base k-index is PERMUTED: feat k = pos*64+cout (w1 planes permuted to match);
// history tail [36864,36954) identity. KP = 36960 (= 33*35*32)
#define FEAT   36864
#define HIST   90
#define K1     36954
#define KP     36960

typedef __attribute__((ext_vector_type(8))) short short8;
typedef __attribute__((ext_vector_type(4))) float f32x4;
typedef __attribute__((ext_vector_type(2))) int int2v;

__device__ __forceinline__ unsigned short f2bf(float x) {
  unsigned u = __float_as_uint(x);
  return (unsigned short)((u + 0x7FFFu + ((u >> 16) & 1u)) >> 16);
}
__device__ __forceinline__ float bf2f(unsigned short h) {
  return __uint_as_float(((unsigned)h) << 16);
}

// packed hi/lo split of 8 fp32 via v_cvt_pk_bf16_f32 (RNE): ~6 VALU per 2 elems
__device__ __forceinline__ short8 cvt_hi_lo8(const float* __restrict__ v, short8& lov) {
  union { unsigned u[4]; short8 s; } H, L;
#pragma unroll
  for (int q = 0; q < 4; ++q) {
    unsigned h, l;
    asm("v_cvt_pk_bf16_f32 %0, %1, %2" : "=v"(h) : "v"(v[2 * q]), "v"(v[2 * q + 1]));
    float h0 = __uint_as_float(h << 16);
    float h1 = __uint_as_float(h & 0xffff0000u);
    asm("v_cvt_pk_bf16_f32 %0, %1, %2" : "=v"(l) : "v"(v[2 * q] - h0), "v"(v[2 * q + 1] - h1));
    H.u[q] = h; L.u[q] = l;
  }
  lov = L.s;
  return H.s;
}

// paired epilogue split: v0,v1 -> hi0,hi1,lo0,lo1 (bit-identical to f2bf path)
__device__ __forceinline__ void cvt2(float v0, float v1, unsigned& hp, unsigned& lp) {
  asm("v_cvt_pk_bf16_f32 %0, %1, %2" : "=v"(hp) : "v"(v0), "v"(v1));
  float h0 = __uint_as_float(hp << 16);
  float h1 = __uint_as_float(hp & 0xffff0000u);
  asm("v_cvt_pk_bf16_f32 %0, %1, %2" : "=v"(lp) : "v"(v0 - h0), "v"(v1 - h1));
}

// ---- merged small preprocessing: w1c | w2 | w3 | fc2-transpose | w1 tail ----
// ranges: [0,6144) w1c; [6144,38912) w2; [38912,75776) w3;
//         [75776,108544) fc2 transpose; [108544,120832) w1 tail. grid 472x256.
__global__ __launch_bounds__(256) void convert_small(const float* __restrict__ c1w,
    const float* __restrict__ c2w, const float* __restrict__ c3w,
    const float* __restrict__ f1w, const float* __restrict__ f2w,
    unsigned short* __restrict__ w1chi, unsigned short* __restrict__ w1clo,
    unsigned short* __restrict__ w2hi, unsigned short* __restrict__ w2lo,
    unsigned short* __restrict__ w3hi, unsigned short* __restrict__ w3lo,
    float* __restrict__ wT2,
    unsigned short* __restrict__ w1hi, unsigned short* __restrict__ w1lo)
{
  int i = blockIdx.x * 256 + threadIdx.x;
  if (i < 6144) {
    int kw = i & 7, rest = i >> 3;
    int cout = rest & 31, pair = rest >> 5;
    int c = pair >> 3, kh = pair & 7;
    float x = c1w[((cout * 3 + c) * 8 + kh) * 8 + kw];
    unsigned short h = f2bf(x);
    w1chi[i] = h; w1clo[i] = f2bf(x - bf2f(h));
  } else if (i < 38912) {
    int j = i - 6144;
    int tap = j >> 11, rem = j & 2047;
    int co = rem >> 5, ci = rem & 31;
    float x = c2w[co * 512 + ci * 16 + tap];
    unsigned short h = f2bf(x);
    w2hi[j] = h; w2lo[j] = f2bf(x - bf2f(h));
  } else if (i < 75776) {
    int j = i - 38912;
    int tap = j >> 12, rem = j & 4095;
    int cout = rem >> 6, cin = rem & 63;
    float x = c3w[cout * 576 + cin * 9 + tap];
    unsigned short h = f2bf(x);
    w3hi[j] = h; w3lo[j] = f2bf(x - bf2f(h));
  } else if (i < 108544) {
    int j = i - 75776;
    int r = j >> 8, c = j & 255;
    wT2[j] = f2w[c * 128 + r];
  } else if (i < 120832) {
    int j = i - 108544;
    int o = j / 96, t = j % 96;
    int k = FEAT + t;
    float x = (k < K1) ? f1w[(size_t)o * K1 + k] : 0.f;
    unsigned short h = f2bf(x);
    size_t p = (size_t)o * KP + k;
    w1hi[p] = h; w1lo[p] = f2bf(x - bf2f(h));
  }
}

// ---- conv1 MFMA bf16x4, fused fp32->bf16 hi/lo via packed cvt ----
__global__ __launch_bounds__(256) void conv1_mfma(const float* __restrict__ state,
    const unsigned short* __restrict__ whi, const unsigned short* __restrict__ wlo,
    const float* __restrict__ bias, unsigned short* __restrict__ ohi,
    unsigned short* __restrict__ olo, int batch0)
{
  int wv = threadIdx.x >> 6, lane = threadIdx.x & 63;
  int b = blockIdx.y;             // local batch 0..127
  int l15 = lane & 15, kg = lane >> 4;
  int posbase = blockIdx.x * 192 + wv * 48;
  int rowb[3];
#pragma unroll
  for (int i = 0; i < 3; ++i) {
    int pos = posbase + i * 16 + l15;
    int cp = pos > 3024 ? 3024 : pos;
    int y = cp / 55, x = cp % 55;
    rowb[i] = (y * 4) * 224 + x * 4;
  }
  const float* ip = state + (size_t)(batch0 + b) * 150528;
  f32x4 acc[3][2];
#pragma unroll
  for (int i = 0; i < 3; ++i) {
    acc[i][0] = (f32x4){0.f, 0.f, 0.f, 0.f};
    acc[i][1] = (f32x4){0.f, 0.f, 0.f, 0.f};
  }
#pragma unroll 2
  for (int s = 0; s < 6; ++s) {
    int pair = s * 4 + kg;
    int c = pair >> 3, kh = pair & 7;
    int aoff = c * 50176 + kh * 224;
    short8 Ah[3], Al[3], Bh[2], Bl[2];
#pragma unroll
    for (int i = 0; i < 3; ++i) {
      const float* p = ip + aoff + rowb[i];
      const float4 f0 = *(const float4*)p;
      const float4 f1 = *(const float4*)(p + 4);
      float v[8] = {f0.x, f0.y, f0.z, f0.w, f1.x, f1.y, f1.z, f1.w};
      Ah[i] = cvt_hi_lo8(v, Al[i]);
    }
    int wb = (pair * 32 + l15) * 8;
#pragma unroll
    for (int nt = 0; nt < 2; ++nt) {
      Bh[nt] = *(const short8*)(whi + wb + nt * 128);
      Bl[nt] = *(const short8*)(wlo + wb + nt * 128);
    }
#pragma unroll
    for (int i = 0; i < 3; ++i)
#pragma unroll
      for (int nt = 0; nt < 2; ++nt) {
        acc[i][nt] = __builtin_amdgcn_mfma_f32_16x16x32_bf16(Ah[i], Bh[nt], acc[i][nt], 0, 0, 0);
        acc[i][nt] = __builtin_amdgcn_mfma_f32_16x16x32_bf16(Ah[i], Bl[nt], acc[i][nt], 0, 0, 0);
        acc[i][nt] = __builtin_amdgcn_mfma_f32_16x16x32_bf16(Al[i], Bh[nt], acc[i][nt], 0, 0, 0);
        acc[i][nt] = __builtin_amdgcn_mfma_f32_16x16x32_bf16(Al[i], Bl[nt], acc[i][nt], 0, 0, 0);
      }
  }
  float bv0 = bias[l15], bv1 = bias[16 + l15];
#pragma unroll
  for (int i = 0; i < 3; ++i) {
#pragma unroll
    for (int r = 0; r < 4; ++r) {
      int pos = posbase + i * 16 + kg * 4 + r;
      if (pos < 3025) {
        size_t o = ((size_t)b * 3025 + pos) * 32 + l15;
        float v0 = acc[i][0][r] + bv0; v0 = v0 > 0.f ? v0 : 0.f;
        float v1 = acc[i][1][r] + bv1; v1 = v1 > 0.f ? v1 : 0.f;
        unsigned hp, lp;
        cvt2(v0, v1, hp, lp);
        ohi[o]      = (unsigned short)(hp & 0xffff);
        ohi[o + 16] = (unsigned short)(hp >> 16);
        olo[o]      = (unsigned short)(lp & 0xffff);
        olo[o + 16] = (unsigned short)(lp >> 16);
      }
    }
  }
}

// ---- conv2 MFMA bf16x3: wave = 2 batches x 48 pos x 64 cout ----
__global__ __launch_bounds__(256) void conv2_mfma(const unsigned short* __restrict__ xhi,
    const unsigned short* __restrict__ xlo, const unsigned short* __restrict__ whi,
    const unsigned short* __restrict__ wlo, const float* __restrict__ bias,
    unsigned short* __restrict__ ohi, unsigned short* __restrict__ olo, int batch0)
{
  int wv = threadIdx.x >> 6, lane = threadIdx.x & 63;
  int b0 = blockIdx.y * 2;            // local batch pair
  int l15 = lane & 15, kg = lane >> 4;
  int posbase = blockIdx.x * 192 + wv * 48;
  int pv[3];
#pragma unroll
  for (int i = 0; i < 3; ++i) {
    int pos = posbase + i * 16 + l15;
    int cp = pos > 675 ? 675 : pos;
    int y = cp / 26, x = cp % 26;
    pv[i] = (2 * y) * 55 + 2 * x;     // input base position index
  }
  size_t ibase0 = (size_t)b0 * 96800;       // 3025*32
  size_t ibase1 = ibase0 + 96800;
  int ibn[4];
#pragma unroll
  for (int nt = 0; nt < 4; ++nt) ibn[nt] = (nt * 16 + l15) * 32 + kg * 8;
  f32x4 acc[2][3][4];
#pragma unroll
  for (int bb = 0; bb < 2; ++bb)
#pragma unroll
    for (int i = 0; i < 3; ++i)
#pragma unroll
      for (int nt = 0; nt < 4; ++nt) acc[bb][i][nt] = (f32x4){0.f, 0.f, 0.f, 0.f};

#pragma unroll 2
  for (int tap = 0; tap < 16; ++tap) {
    int kh = tap >> 2, kw = tap & 3;
    int wb = tap * 2048;
    short8 A0h[3], A0l[3], A1h[3], A1l[3], Bh[4], Bl[4];
#pragma unroll
    for (int i = 0; i < 3; ++i) {
      int ia = (pv[i] + kh * 55 + kw) * 32 + kg * 8;
      A0h[i] = *(const short8*)(xhi + ibase0 + ia);
      A0l[i] = *(const short8*)(xlo + ibase0 + ia);
      A1h[i] = *(const short8*)(xhi + ibase1 + ia);
      A1l[i] = *(const short8*)(xlo + ibase1 + ia);
    }
#pragma unroll
    for (int nt = 0; nt < 4; ++nt) {
      Bh[nt] = *(const short8*)(whi + wb + ibn[nt]);
      Bl[nt] = *(const short8*)(wlo + wb + ibn[nt]);
    }
#pragma unroll
    for (int i = 0; i < 3; ++i)
#pragma unroll
      for (int nt = 0; nt < 4; ++nt) {
        acc[0][i][nt] = __builtin_amdgcn_mfma_f32_16x16x32_bf16(A0h[i], Bh[nt], acc[0][i][nt], 0, 0, 0);
        acc[0][i][nt] = __builtin_amdgcn_mfma_f32_16x16x32_bf16(A0h[i], Bl[nt], acc[0][i][nt], 0, 0, 0);
        acc[0][i][nt] = __builtin_amdgcn_mfma_f32_16x16x32_bf16(A0l[i], Bh[nt], acc[0][i][nt], 0, 0, 0);
        acc[1][i][nt] = __builtin_amdgcn_mfma_f32_16x16x32_bf16(A1h[i], Bh[nt], acc[1][i][nt], 0, 0, 0);
        acc[1][i][nt] = __builtin_amdgcn_mfma_f32_16x16x32_bf16(A1h[i], Bl[nt], acc[1][i][nt], 0, 0, 0);
        acc[1][i][nt] = __builtin_amdgcn_mfma_f32_16x16x32_bf16(A1l[i], Bh[nt], acc[1][i][nt], 0, 0, 0);
      }
  }
  float bv[4];
#pragma unroll
  for (int nt = 0; nt < 4; ++nt) bv[nt] = bias[nt * 16 + l15];
#pragma unroll
  for (int bb = 0; bb < 2; ++bb) {
    size_t obase = (size_t)(batch0 + b0 + bb) * 676;
#pragma unroll
    for (int i = 0; i < 3; ++i) {
#pragma unroll
      for (int r = 0; r < 4; ++r) {
        int pos = posbase + i * 16 + kg * 4 + r;
        if (pos < 676) {
          size_t o = (obase + pos) * 64 + l15;
#pragma unroll
          for (int np = 0; np < 2; ++np) {
            float v0 = acc[bb][i][2 * np][r] + bv[2 * np];         v0 = v0 > 0.f ? v0 : 0.f;
            float v1 = acc[bb][i][2 * np + 1][r] + bv[2 * np + 1]; v1 = v1 > 0.f ? v1 : 0.f;
            unsigned hp, lp;
            cvt2(v0, v1, hp, lp);
            ohi[o + (2 * np) * 16]     = (unsigned short)(hp & 0xffff);
            ohi[o + (2 * np + 1) * 16] = (unsigned short)(hp >> 16);
            olo[o + (2 * np) * 16]     = (unsigned short)(lp & 0xffff);
            olo[o + (2 * np + 1) * 16] = (unsigned short)(lp >> 16);
          }
        }
      }
    }
  }
}

// ---- conv3 MFMA bf16x3: 4 waves/block, 192 pos, 10-row cin-split slab ----
__global__ __launch_bounds__(256) void conv3_mfma(const unsigned short* __restrict__ xhi,
    const unsigned short* __restrict__ xlo, const unsigned short* __restrict__ whi,
    const unsigned short* __restrict__ wlo, const float* __restrict__ bias,
    unsigned short* __restrict__ bhi, unsigned short* __restrict__ blo)
{
  __shared__ unsigned short slabh[260 * 40];   // 20800 B
  __shared__ unsigned short slabl[260 * 40];
  int t = threadIdx.x;
  int wv = t >> 6, lane = t & 63;
  int pchunk = blockIdx.x;    // 0..2 (8 output rows each)
  int b = blockIdx.y;         // 0..255
  const unsigned short* gh = xhi + (size_t)b * 43264 + pchunk * 13312;  // 8*26*64
  const unsigned short* gl = xlo + (size_t)b * 43264 + pchunk * 13312;
  int l15 = lane & 15, kg = lane >> 4;
  int posbase = pchunk * 192 + wv * 48;
  int lr[3], lx[3];
#pragma unroll
  for (int i = 0; i < 3; ++i) {
    int pos = posbase + i * 16 + l15;
    int y = pos / 24, x = pos % 24;
    lr[i] = y - pchunk * 8;      // 0..7
    lx[i] = x;
  }
  int ibn[4];
#pragma unroll
  for (int nt = 0; nt < 4; ++nt) ibn[nt] = (nt * 16 + l15) * 64 + kg * 8;
  f32x4 acc[3][4];
#pragma unroll
  for (int i = 0; i < 3; ++i)
#pragma unroll
    for (int nt = 0; nt < 4; ++nt) acc[i][nt] = (f32x4){0.f, 0.f, 0.f, 0.f};

#pragma unroll 1
  for (int ks = 0; ks < 2; ++ks) {
    if (ks) __syncthreads();
    for (int e = t; e < 1040; e += 256) {     // 260 pos x 4 chunks of 8 shorts
      int p = e >> 2, s = e & 3;
      *(short8*)(slabh + p * 40 + s * 8) = *(const short8*)(gh + p * 64 + ks * 32 + s * 8);
      *(short8*)(slabl + p * 40 + s * 8) = *(const short8*)(gl + p * 64 + ks * 32 + s * 8);
    }
    __syncthreads();
    int ko = ks * 32;
#pragma unroll 3
    for (int tap = 0; tap < 9; ++tap) {
      int kh = tap / 3, kw = tap % 3;
      int wboff = tap * 4096 + ko;
      short8 Ah[3], Al[3], Bh[4], Bl[4];
#pragma unroll
      for (int i = 0; i < 3; ++i) {
        int p = (lr[i] + kh) * 26 + lx[i] + kw;    // 0..259
        int d = p * 40 + kg * 8;
        Ah[i] = *(const short8*)(slabh + d);
        Al[i] = *(const short8*)(slabl + d);
      }
#pragma unroll
      for (int nt = 0; nt < 4; ++nt) {
        Bh[nt] = *(const short8*)(whi + wboff + ibn[nt]);
        Bl[nt] = *(const short8*)(wlo + wboff + ibn[nt]);
      }
#pragma unroll
      for (int i = 0; i < 3; ++i)
#pragma unroll
        for (int nt = 0; nt < 4; ++nt) {
          acc[i][nt] = __builtin_amdgcn_mfma_f32_16x16x32_bf16(Ah[i], Bh[nt], acc[i][nt], 0, 0, 0);
          acc[i][nt] = __builtin_amdgcn_mfma_f32_16x16x32_bf16(Ah[i], Bl[nt], acc[i][nt], 0, 0, 0);
          acc[i][nt] = __builtin_amdgcn_mfma_f32_16x16x32_bf16(Al[i], Bh[nt], acc[i][nt], 0, 0, 0);
        }
    }
  }
  float bv[4];
#pragma unroll
  for (int nt = 0; nt < 4; ++nt) bv[nt] = bias[nt * 16 + l15];
  size_t ob = (size_t)b * KP;
#pragma unroll
  for (int i = 0; i < 3; ++i) {
#pragma unroll
    for (int r = 0; r < 4; ++r) {
      int pos = posbase + i * 16 + kg * 4 + r;
      size_t o = ob + (size_t)pos * 64 + l15;
#pragma unroll
      for (int np = 0; np < 2; ++np) {
        float v0 = acc[i][2 * np][r] + bv[2 * np];         v0 = v0 > 0.f ? v0 : 0.f;
        float v1 = acc[i][2 * np + 1][r] + bv[2 * np + 1]; v1 = v1 > 0.f ? v1 : 0.f;
        unsigned hp, lp;
        cvt2(v0, v1, hp, lp);
        bhi[o + (2 * np) * 16]     = (unsigned short)(hp & 0xffff);
        bhi[o + (2 * np + 1) * 16] = (unsigned short)(hp >> 16);
        blo[o + (2 * np) * 16]     = (unsigned short)(lp & 0xffff);
        blo[o + (2 * np + 1) * 16] = (unsigned short)(lp >> 16);
      }
    }
  }
}

// ---- fill history tail + zero pad of base planes: k in [36864, 36960), identity ----
// (must run after conv passes: base planes alias the c1 region)
__global__ __launch_bounds__(128) void fill_hist(const float* __restrict__ hist,
    unsigned short* __restrict__ bhi, unsigned short* __restrict__ blo)
{
  int b = blockIdx.x, t = threadIdx.x;
  int k = FEAT + t;
  if (k >= KP) return;
  float x = (k < K1) ? hist[b * HIST + t] : 0.f;
  unsigned short h = f2bf(x);
  size_t o = (size_t)b * KP + k;
  bhi[o] = h; blo[o] = f2bf(x - bf2f(h));
}

// ---- fc1 weights feat part, PERMUTED to pos-major: dst[o][pos*64+c] = w[o][c*576+pos] ----
__global__ __launch_bounds__(256) void convert_w1(const float* __restrict__ w,
    unsigned short* __restrict__ hi, unsigned short* __restrict__ lo)
{
  __shared__ float tl[64][65];
  int o = blockIdx.y;
  int p0 = blockIdx.x * 64;
  int t = threadIdx.x;
  const float* src = w + (size_t)o * K1;
  for (int e = t; e < 4096; e += 256) {
    int c = e >> 6, p = e & 63;
    tl[p][c] = src[c * 576 + p0 + p];
  }
  __syncthreads();
  size_t dbase = (size_t)o * KP;
  for (int e = t; e < 4096; e += 256) {
    int p = e >> 6, c = e & 63;
    float x = tl[p][c];
    unsigned short h = f2bf(x);
    size_t d = dbase + (size_t)(p0 + p) * 64 + c;
    hi[d] = h; lo[d] = f2bf(x - bf2f(h));
  }
}

// ---- fc1 MFMA bf16x3 split-K (round-22 config: 32 samples x 16 outs) ----
__global__ __launch_bounds__(256) void fc1_mfma(const unsigned short* __restrict__ bhi,
    const unsigned short* __restrict__ blo, const unsigned short* __restrict__ whi,
    const unsigned short* __restrict__ wlo, float* __restrict__ part)
{
  int w = threadIdx.x >> 6, lane = threadIdx.x & 63;
  int job = blockIdx.x * 4 + w;        // 0..63
  int mt2 = job & 7, nt = job >> 3;
  int ks = blockIdx.y;                 // 0..32
  int k0 = ks * 35 * 32;
  int l15 = lane & 15, kg = lane >> 4;
  int s0 = mt2 * 32 + l15;
  int o  = nt * 16 + l15;
  const unsigned short* pa0h = bhi + (size_t)s0 * KP + k0 + kg * 8;
  const unsigned short* pa1h = pa0h + (size_t)16 * KP;
  const unsigned short* pa0l = blo + (size_t)s0 * KP + k0 + kg * 8;
  const unsigned short* pa1l = pa0l + (size_t)16 * KP;
  const unsigned short* pbh  = whi + (size_t)o * KP + k0 + kg * 8;
  const unsigned short* pbl  = wlo + (size_t)o * KP + k0 + kg * 8;
  f32x4 acc0 = {0.f, 0.f, 0.f, 0.f}, acc1 = {0.f, 0.f, 0.f, 0.f};
#pragma unroll 1
  for (int i = 0; i < 35; ++i) {
    short8 a0h = *(const short8*)pa0h;
    short8 a1h = *(const short8*)pa1h;
    short8 a0l = *(const short8*)pa0l;
    short8 a1l = *(const short8*)pa1l;
    short8 bh  = *(const short8*)pbh;
    short8 bl  = *(const short8*)pbl;
    acc0 = __builtin_amdgcn_mfma_f32_16x16x32_bf16(a0h, bh, acc0, 0, 0, 0);
    acc1 = __builtin_amdgcn_mfma_f32_16x16x32_bf16(a1h, bh, acc1, 0, 0, 0);
    acc0 = __builtin_amdgcn_mfma_f32_16x16x32_bf16(a0h, bl, acc0, 0, 0, 0);
    acc1 = __builtin_amdgcn_mfma_f32_16x16x32_bf16(a1h, bl, acc1, 0, 0, 0);
    acc0 = __builtin_amdgcn_mfma_f32_16x16x32_bf16(a0l, bh, acc0, 0, 0, 0);
    acc1 = __builtin_amdgcn_mfma_f32_16x16x32_bf16(a1l, bh, acc1, 0, 0, 0);
    pa0h += 32; pa1h += 32; pa0l += 32; pa1l += 32; pbh += 32; pbl += 32;
  }
  float* pp0 = part + (((size_t)ks * 64 + job) * 2) * 256;
  float* pp1 = pp0 + 256;
#pragma unroll
  for (int r = 0; r < 4; ++r) {
    pp0[r * 64 + lane] = acc0[r];
    pp1[r * 64 + lane] = acc1[r];
  }
}

// ---- fixed-order split-K reduce (round-22 layout) ----
__global__ __launch_bounds__(256) void fc1_reduce(const float* __restrict__ part,
                                                  float* __restrict__ h1)
{
  int i = blockIdx.x * 256 + threadIdx.x;
  if (i >= 32768) return;
  int s = i >> 7, o = i & 127;
  int mt2 = s >> 5, ti = (s >> 4) & 1, nt = o >> 4;
  int job = nt * 8 + mt2;
  int r = s & 15, c = o & 15;
  int off = (job * 2 + ti) * 256 + (r & 3) * 64 + ((r >> 2) << 4) + c;
  float sum = 0.f;
#pragma unroll 1
  for (int ks = 0; ks < 33; ++ks) sum += part[(size_t)ks * 32768 + off];
  h1[i] = sum;
}

// ---------------- SNN simulation: branchless unrolled fc2 matvec ----------------
__global__ __launch_bounds__(256) void snn_ker(const float* __restrict__ h1,
    const float* __restrict__ b1, const float* __restrict__ w2T,
    const float* __restrict__ b2p, const float* __restrict__ w3,
    const float* __restrict__ b3p, float* __restrict__ out)
{
  int b = blockIdx.x, t = threadIdx.x;
  __shared__ float spk1l[128];
  __shared__ float part[4][9];
  float h1v = 0.f;
  if (t < 128) h1v = h1[b * 128 + t] + b1[t];
  float b2 = b2p[t];
  float w3r[9];
#pragma unroll
  for (int j = 0; j < 9; ++j) w3r[j] = w3[j * 256 + t];
  float mem1 = 0.f, syn1 = 0.f, mem2 = 0.f, syn2 = 0.f;
  float syn3[9], mem3[9], pot[9];
#pragma unroll
  for (int j = 0; j < 9; ++j) { syn3[j] = 0.f; mem3[j] = 0.f; pot[j] = 0.f; }

#pragma unroll 1
  for (int step = 0; step < 10; ++step) {
    if (t < 128) {
      syn1 = ALPHA * syn1 + h1v;
      mem1 = BETA * mem1 + syn1;
      float s = (mem1 > 1.0f) ? 1.f : 0.f;
      spk1l[t] = s;
      mem1 -= s;
    }
    __syncthreads();
    float h2 = b2;
#pragma unroll
    for (int i = 0; i < 128; ++i) {
      h2 += spk1l[i] * w2T[i * 256 + t];
    }
    syn2 = ALPHA * syn2 + h2;
    mem2 = BETA * mem2 + syn2;
    float s2 = (mem2 > 1.0f) ? 1.f : 0.f;
    mem2 -= s2;

    float v[9];
#pragma unroll
    for (int j = 0; j < 9; ++j) v[j] = s2 * w3r[j];
#pragma unroll
    for (int j = 0; j < 9; ++j) {
      v[j] += __shfl_down(v[j], 32);
      v[j] += __shfl_down(v[j], 16);
      v[j] += __shfl_down(v[j], 8);
      v[j] += __shfl_down(v[j], 4);
      v[j] += __shfl_down(v[j], 2);
      v[j] += __shfl_down(v[j], 1);
    }
    if ((t & 63) == 0) {
#pragma unroll
      for (int j = 0; j < 9; ++j) part[t >> 6][j] = v[j];
    }
    __syncthreads();
    if (t == 0) {
#pragma unroll
      for (int j = 0; j < 9; ++j) {
        float h3 = part[0][j] + part[1][j] + part[2][j] + part[3][j] + b3p[j];
        syn3[j] = ALPHA * syn3[j] + h3;
        mem3[j] = BETA * mem3[j] + syn3[j];
        pot[j] += mem3[j];
      }
    }
  }
  if (t == 0) {
#pragma unroll
    for (int j = 0; j < 9; ++j) out[b * 9 + j] = pot[j] / 10.0f;
  }
}

// ---------------- host ----------------
extern "C" void kernel_launch(void* const* d_in, const int* in_sizes, int n_in,
                              void* d_out, int out_size, void* d_ws, size_t ws_size,
                              hipStream_t stream)
{
  const float* state = (const float*)d_in[0];
  const float* hist  = (const float*)d_in[1];
  const float* c1w   = (const float*)d_in[2];
  const float* c1b   = (const float*)d_in[3];
  const float* c2w   = (const float*)d_in[4];
  const float* c2b   = (const float*)d_in[5];
  const float* c3w   = (const float*)d_in[6];
  const float* c3b   = (const float*)d_in[7];
  const float* f1w   = (const float*)d_in[8];
  const float* f1b   = (const float*)d_in[9];
  const float* f2w   = (const float*)d_in[10];
  const float* f2b   = (const float*)d_in[11];
  const float* f3w   = (const float*)d_in[12];
  const float* f3b   = (const float*)d_in[13];
  float* out = (float*)d_out;
  float* ws  = (float*)d_ws;

  // workspace (float offsets), peak 29,419,520 floats (117.7 MB):
  //   c1hi [0, 6,195,200) c1lo [6,195,200, 12,390,400)       (half-batch, reused per pass;
  //        region later reused as base_hi [0, 4,730,880) base_lo [4,730,880, 9,461,760))
  //   c2hi [12,390,400, 17,928,192) c2lo [17,928,192, 23,465,984)  (full batch)
  //   w1_hi [23,465,984, 25,831,424) w1_lo [25,831,424, 28,196,864)
  //   partb [28,196,864, 29,278,208)
  //   w1chi [29,278,208, 29,281,280) w1clo [29,281,280, 29,284,352)
  //   w2hi [29,284,352, 29,300,736) w2lo [29,300,736, 29,317,120)
  //   w3hi [29,317,120, 29,335,552) w3lo [29,335,552, 29,353,984)
  //   h1 [29,353,984, 29,386,752) wT2 [29,386,752, 29,419,520)
  unsigned short* c1hi    = (unsigned short*)(ws);
  unsigned short* c1lo    = (unsigned short*)(ws + 6195200);
  unsigned short* base_hi = (unsigned short*)(ws);
  unsigned short* base_lo = (unsigned short*)(ws + 4730880);
  unsigned short* c2hi    = (unsigned short*)(ws + 12390400);
  unsigned short* c2lo    = (unsigned short*)(ws + 17928192);
  unsigned short* w1_hi   = (unsigned short*)(ws + 23465984);
  unsigned short* w1_lo   = (unsigned short*)(ws + 25831424);
  float* partb    = ws + 28196864;
  unsigned short* w1chi   = (unsigned short*)(ws + 29278208);
  unsigned short* w1clo   = (unsigned short*)(ws + 29281280);
  unsigned short* w2_hi   = (unsigned short*)(ws + 29284352);
  unsigned short* w2_lo   = (unsigned short*)(ws + 29300736);
  unsigned short* w3_hi   = (unsigned short*)(ws + 29317120);
  unsigned short* w3_lo   = (unsigned short*)(ws + 29335552);
  float* h1buf    = ws + 29353984;
  float* wT2      = ws + 29386752;

  // merged small preprocessing (w1c, w2, w3, fc2-transpose, w1 tail)
  convert_small<<<dim3(472), 256, 0, stream>>>(c1w, c2w, c3w, f1w, f2w,
                                               w1chi, w1clo, w2_hi, w2_lo,
                                               w3_hi, w3_lo, wT2, w1_hi, w1_lo);
  // half-batch conv1 -> conv2 passes (conv1 reads fp32 state directly)
  for (int p = 0; p < 2; ++p) {
    conv1_mfma<<<dim3(16, 128), 256, 0, stream>>>(state, w1chi, w1clo, c1b,
                                                  c1hi, c1lo, p * 128);
    conv2_mfma<<<dim3(4, 64), 256, 0, stream>>>(c1hi, c1lo, w2_hi, w2_lo, c2b,
                                                c2hi, c2lo, p * 128);
  }
  // c1 dead -> region reused for base planes
  convert_w1<<<dim3(9, 128), 256, 0, stream>>>(f1w, w1_hi, w1_lo);
  fill_hist<<<dim3(256), 128, 0, stream>>>(hist, base_hi, base_lo);
  conv3_mfma<<<dim3(3, 256), 256, 0, stream>>>(c2hi, c2lo, w3_hi, w3_lo, c3b,
                                               base_hi, base_lo);
  fc1_mfma<<<dim3(16, 33), 256, 0, stream>>>(base_hi, base_lo, w1_hi, w1_lo, partb);
  fc1_reduce<<<dim3(128), 256, 0, stream>>>(partb, h1buf);
  snn_ker<<<dim3(256), 256, 0, stream>>>(h1buf, f1b, wT2, f2b, f3w, f3b, out);
}

// Round 25
// 335.983 us; speedup vs baseline: 1.0628x; 1.0230x over previous
//
#include <hip/hip_runtime.h>
#include <cstddef>
#include <cstdint>

#define ALPHA 0.9f
#define BETA  0.8f

// ---------------- sizes ----------------
// conv1: 32x3x8x8 s4 -> [256,32,55,55]   (MFMA bf16x4, fused conversion via v_cvt_pk_bf16_f32)
// conv2: 64x32x4x4 s2 -> [256,64,26,26]  (MFMA bf16x3, 2-batch x 48 pos x 64 cout wave tile)
// conv3: 64x64x3x3 s1 -> [256,64,24,24]  (MFMA bf16x3, cin-split two-phase LDS slab)
// fc1:   split-K MFMA bf16x3, wave = 32 samples x 16 outs; reduce fused into snn_ker
// Small weight conversions merged (convert_small); w1-permute + hist tail merged (prep_fc1).
// base k-index is PERMUTED: feat k = pos*64+cout (w1 planes permuted to match);
// history tail [36864,36954) identity. KP = 36960 (= 33*35*32)
#define FEAT   36864
#define HIST   90
#define K1     36954
#define KP     36960

typedef __attribute__((ext_vector_type(8))) short short8;
typedef __attribute__((ext_vector_type(4))) float f32x4;
typedef __attribute__((ext_vector_type(2))) int int2v;

__device__ __forceinline__ unsigned short f2bf(float x) {
  unsigned u = __float_as_uint(x);
  return (unsigned short)((u + 0x7FFFu + ((u >> 16) & 1u)) >> 16);
}
__device__ __forceinline__ float bf2f(unsigned short h) {
  return __uint_as_float(((unsigned)h) << 16);
}

// packed hi/lo split of 8 fp32 via v_cvt_pk_bf16_f32 (RNE): ~6 VALU per 2 elems
__device__ __forceinline__ short8 cvt_hi_lo8(const float* __restrict__ v, short8& lov) {
  union { unsigned u[4]; short8 s; } H, L;
#pragma unroll
  for (int q = 0; q < 4; ++q) {
    unsigned h, l;
    asm("v_cvt_pk_bf16_f32 %0, %1, %2" : "=v"(h) : "v"(v[2 * q]), "v"(v[2 * q + 1]));
    float h0 = __uint_as_float(h << 16);
    float h1 = __uint_as_float(h & 0xffff0000u);
    asm("v_cvt_pk_bf16_f32 %0, %1, %2" : "=v"(l) : "v"(v[2 * q] - h0), "v"(v[2 * q + 1] - h1));
    H.u[q] = h; L.u[q] = l;
  }
  lov = L.s;
  return H.s;
}

// paired epilogue split: v0,v1 -> hi0,hi1,lo0,lo1 (bit-identical to f2bf path)
__device__ __forceinline__ void cvt2(float v0, float v1, unsigned& hp, unsigned& lp) {
  asm("v_cvt_pk_bf16_f32 %0, %1, %2" : "=v"(hp) : "v"(v0), "v"(v1));
  float h0 = __uint_as_float(hp << 16);
  float h1 = __uint_as_float(hp & 0xffff0000u);
  asm("v_cvt_pk_bf16_f32 %0, %1, %2" : "=v"(lp) : "v"(v0 - h0), "v"(v1 - h1));
}

// ---- merged small preprocessing: w1c | w2 | w3 | fc2-transpose | w1 tail ----
// ranges: [0,6144) w1c; [6144,38912) w2; [38912,75776) w3;
//         [75776,108544) fc2 transpose; [108544,120832) w1 tail. grid 472x256.
__global__ __launch_bounds__(256) void convert_small(const float* __restrict__ c1w,
    const float* __restrict__ c2w, const float* __restrict__ c3w,
    const float* __restrict__ f1w, const float* __restrict__ f2w,
    unsigned short* __restrict__ w1chi, unsigned short* __restrict__ w1clo,
    unsigned short* __restrict__ w2hi, unsigned short* __restrict__ w2lo,
    unsigned short* __restrict__ w3hi, unsigned short* __restrict__ w3lo,
    float* __restrict__ wT2,
    unsigned short* __restrict__ w1hi, unsigned short* __restrict__ w1lo)
{
  int i = blockIdx.x * 256 + threadIdx.x;
  if (i < 6144) {
    int kw = i & 7, rest = i >> 3;
    int cout = rest & 31, pair = rest >> 5;
    int c = pair >> 3, kh = pair & 7;
    float x = c1w[((cout * 3 + c) * 8 + kh) * 8 + kw];
    unsigned short h = f2bf(x);
    w1chi[i] = h; w1clo[i] = f2bf(x - bf2f(h));
  } else if (i < 38912) {
    int j = i - 6144;
    int tap = j >> 11, rem = j & 2047;
    int co = rem >> 5, ci = rem & 31;
    float x = c2w[co * 512 + ci * 16 + tap];
    unsigned short h = f2bf(x);
    w2hi[j] = h; w2lo[j] = f2bf(x - bf2f(h));
  } else if (i < 75776) {
    int j = i - 38912;
    int tap = j >> 12, rem = j & 4095;
    int cout = rem >> 6, cin = rem & 63;
    float x = c3w[cout * 576 + cin * 9 + tap];
    unsigned short h = f2bf(x);
    w3hi[j] = h; w3lo[j] = f2bf(x - bf2f(h));
  } else if (i < 108544) {
    int j = i - 75776;
    int r = j >> 8, c = j & 255;
    wT2[j] = f2w[c * 128 + r];
  } else if (i < 120832) {
    int j = i - 108544;
    int o = j / 96, t = j % 96;
    int k = FEAT + t;
    float x = (k < K1) ? f1w[(size_t)o * K1 + k] : 0.f;
    unsigned short h = f2bf(x);
    size_t p = (size_t)o * KP + k;
    w1hi[p] = h; w1lo[p] = f2bf(x - bf2f(h));
  }
}

// ---- conv1 MFMA bf16x4, fused fp32->bf16 hi/lo via packed cvt ----
__global__ __launch_bounds__(256) void conv1_mfma(const float* __restrict__ state,
    const unsigned short* __restrict__ whi, const unsigned short* __restrict__ wlo,
    const float* __restrict__ bias, unsigned short* __restrict__ ohi,
    unsigned short* __restrict__ olo, int batch0)
{
  int wv = threadIdx.x >> 6, lane = threadIdx.x & 63;
  int b = blockIdx.y;             // local batch 0..127
  int l15 = lane & 15, kg = lane >> 4;
  int posbase = blockIdx.x * 192 + wv * 48;
  int rowb[3];
#pragma unroll
  for (int i = 0; i < 3; ++i) {
    int pos = posbase + i * 16 + l15;
    int cp = pos > 3024 ? 3024 : pos;
    int y = cp / 55, x = cp % 55;
    rowb[i] = (y * 4) * 224 + x * 4;
  }
  const float* ip = state + (size_t)(batch0 + b) * 150528;
  f32x4 acc[3][2];
#pragma unroll
  for (int i = 0; i < 3; ++i) {
    acc[i][0] = (f32x4){0.f, 0.f, 0.f, 0.f};
    acc[i][1] = (f32x4){0.f, 0.f, 0.f, 0.f};
  }
#pragma unroll 2
  for (int s = 0; s < 6; ++s) {
    int pair = s * 4 + kg;
    int c = pair >> 3, kh = pair & 7;
    int aoff = c * 50176 + kh * 224;
    short8 Ah[3], Al[3], Bh[2], Bl[2];
#pragma unroll
    for (int i = 0; i < 3; ++i) {
      const float* p = ip + aoff + rowb[i];
      const float4 f0 = *(const float4*)p;
      const float4 f1 = *(const float4*)(p + 4);
      float v[8] = {f0.x, f0.y, f0.z, f0.w, f1.x, f1.y, f1.z, f1.w};
      Ah[i] = cvt_hi_lo8(v, Al[i]);
    }
    int wb = (pair * 32 + l15) * 8;
#pragma unroll
    for (int nt = 0; nt < 2; ++nt) {
      Bh[nt] = *(const short8*)(whi + wb + nt * 128);
      Bl[nt] = *(const short8*)(wlo + wb + nt * 128);
    }
#pragma unroll
    for (int i = 0; i < 3; ++i)
#pragma unroll
      for (int nt = 0; nt < 2; ++nt) {
        acc[i][nt] = __builtin_amdgcn_mfma_f32_16x16x32_bf16(Ah[i], Bh[nt], acc[i][nt], 0, 0, 0);
        acc[i][nt] = __builtin_amdgcn_mfma_f32_16x16x32_bf16(Ah[i], Bl[nt], acc[i][nt], 0, 0, 0);
        acc[i][nt] = __builtin_amdgcn_mfma_f32_16x16x32_bf16(Al[i], Bh[nt], acc[i][nt], 0, 0, 0);
        acc[i][nt] = __builtin_amdgcn_mfma_f32_16x16x32_bf16(Al[i], Bl[nt], acc[i][nt], 0, 0, 0);
      }
  }
  float bv0 = bias[l15], bv1 = bias[16 + l15];
#pragma unroll
  for (int i = 0; i < 3; ++i) {
#pragma unroll
    for (int r = 0; r < 4; ++r) {
      int pos = posbase + i * 16 + kg * 4 + r;
      if (pos < 3025) {
        size_t o = ((size_t)b * 3025 + pos) * 32 + l15;
        float v0 = acc[i][0][r] + bv0; v0 = v0 > 0.f ? v0 : 0.f;
        float v1 = acc[i][1][r] + bv1; v1 = v1 > 0.f ? v1 : 0.f;
        unsigned hp, lp;
        cvt2(v0, v1, hp, lp);
        ohi[o]      = (unsigned short)(hp & 0xffff);
        ohi[o + 16] = (unsigned short)(hp >> 16);
        olo[o]      = (unsigned short)(lp & 0xffff);
        olo[o + 16] = (unsigned short)(lp >> 16);
      }
    }
  }
}

// ---- conv2 MFMA bf16x3: wave = 2 batches x 48 pos x 64 cout ----
__global__ __launch_bounds__(256) void conv2_mfma(const unsigned short* __restrict__ xhi,
    const unsigned short* __restrict__ xlo, const unsigned short* __restrict__ whi,
    const unsigned short* __restrict__ wlo, const float* __restrict__ bias,
    unsigned short* __restrict__ ohi, unsigned short* __restrict__ olo, int batch0)
{
  int wv = threadIdx.x >> 6, lane = threadIdx.x & 63;
  int b0 = blockIdx.y * 2;            // local batch pair
  int l15 = lane & 15, kg = lane >> 4;
  int posbase = blockIdx.x * 192 + wv * 48;
  int pv[3];
#pragma unroll
  for (int i = 0; i < 3; ++i) {
    int pos = posbase + i * 16 + l15;
    int cp = pos > 675 ? 675 : pos;
    int y = cp / 26, x = cp % 26;
    pv[i] = (2 * y) * 55 + 2 * x;     // input base position index
  }
  size_t ibase0 = (size_t)b0 * 96800;       // 3025*32
  size_t ibase1 = ibase0 + 96800;
  int ibn[4];
#pragma unroll
  for (int nt = 0; nt < 4; ++nt) ibn[nt] = (nt * 16 + l15) * 32 + kg * 8;
  f32x4 acc[2][3][4];
#pragma unroll
  for (int bb = 0; bb < 2; ++bb)
#pragma unroll
    for (int i = 0; i < 3; ++i)
#pragma unroll
      for (int nt = 0; nt < 4; ++nt) acc[bb][i][nt] = (f32x4){0.f, 0.f, 0.f, 0.f};

#pragma unroll 2
  for (int tap = 0; tap < 16; ++tap) {
    int kh = tap >> 2, kw = tap & 3;
    int wb = tap * 2048;
    short8 A0h[3], A0l[3], A1h[3], A1l[3], Bh[4], Bl[4];
#pragma unroll
    for (int i = 0; i < 3; ++i) {
      int ia = (pv[i] + kh * 55 + kw) * 32 + kg * 8;
      A0h[i] = *(const short8*)(xhi + ibase0 + ia);
      A0l[i] = *(const short8*)(xlo + ibase0 + ia);
      A1h[i] = *(const short8*)(xhi + ibase1 + ia);
      A1l[i] = *(const short8*)(xlo + ibase1 + ia);
    }
#pragma unroll
    for (int nt = 0; nt < 4; ++nt) {
      Bh[nt] = *(const short8*)(whi + wb + ibn[nt]);
      Bl[nt] = *(const short8*)(wlo + wb + ibn[nt]);
    }
#pragma unroll
    for (int i = 0; i < 3; ++i)
#pragma unroll
      for (int nt = 0; nt < 4; ++nt) {
        acc[0][i][nt] = __builtin_amdgcn_mfma_f32_16x16x32_bf16(A0h[i], Bh[nt], acc[0][i][nt], 0, 0, 0);
        acc[0][i][nt] = __builtin_amdgcn_mfma_f32_16x16x32_bf16(A0h[i], Bl[nt], acc[0][i][nt], 0, 0, 0);
        acc[0][i][nt] = __builtin_amdgcn_mfma_f32_16x16x32_bf16(A0l[i], Bh[nt], acc[0][i][nt], 0, 0, 0);
        acc[1][i][nt] = __builtin_amdgcn_mfma_f32_16x16x32_bf16(A1h[i], Bh[nt], acc[1][i][nt], 0, 0, 0);
        acc[1][i][nt] = __builtin_amdgcn_mfma_f32_16x16x32_bf16(A1h[i], Bl[nt], acc[1][i][nt], 0, 0, 0);
        acc[1][i][nt] = __builtin_amdgcn_mfma_f32_16x16x32_bf16(A1l[i], Bh[nt], acc[1][i][nt], 0, 0, 0);
      }
  }
  float bv[4];
#pragma unroll
  for (int nt = 0; nt < 4; ++nt) bv[nt] = bias[nt * 16 + l15];
#pragma unroll
  for (int bb = 0; bb < 2; ++bb) {
    size_t obase = (size_t)(batch0 + b0 + bb) * 676;
#pragma unroll
    for (int i = 0; i < 3; ++i) {
#pragma unroll
      for (int r = 0; r < 4; ++r) {
        int pos = posbase + i * 16 + kg * 4 + r;
        if (pos < 676) {
          size_t o = (obase + pos) * 64 + l15;
#pragma unroll
          for (int np = 0; np < 2; ++np) {
            float v0 = acc[bb][i][2 * np][r] + bv[2 * np];         v0 = v0 > 0.f ? v0 : 0.f;
            float v1 = acc[bb][i][2 * np + 1][r] + bv[2 * np + 1]; v1 = v1 > 0.f ? v1 : 0.f;
            unsigned hp, lp;
            cvt2(v0, v1, hp, lp);
            ohi[o + (2 * np) * 16]     = (unsigned short)(hp & 0xffff);
            ohi[o + (2 * np + 1) * 16] = (unsigned short)(hp >> 16);
            olo[o + (2 * np) * 16]     = (unsigned short)(lp & 0xffff);
            olo[o + (2 * np + 1) * 16] = (unsigned short)(lp >> 16);
          }
        }
      }
    }
  }
}

// ---- conv3 MFMA bf16x3: 4 waves/block, 192 pos, 10-row cin-split slab ----
__global__ __launch_bounds__(256) void conv3_mfma(const unsigned short* __restrict__ xhi,
    const unsigned short* __restrict__ xlo, const unsigned short* __restrict__ whi,
    const unsigned short* __restrict__ wlo, const float* __restrict__ bias,
    unsigned short* __restrict__ bhi, unsigned short* __restrict__ blo)
{
  __shared__ unsigned short slabh[260 * 40];   // 20800 B
  __shared__ unsigned short slabl[260 * 40];
  int t = threadIdx.x;
  int wv = t >> 6, lane = t & 63;
  int pchunk = blockIdx.x;    // 0..2 (8 output rows each)
  int b = blockIdx.y;         // 0..255
  const unsigned short* gh = xhi + (size_t)b * 43264 + pchunk * 13312;  // 8*26*64
  const unsigned short* gl = xlo + (size_t)b * 43264 + pchunk * 13312;
  int l15 = lane & 15, kg = lane >> 4;
  int posbase = pchunk * 192 + wv * 48;
  int lr[3], lx[3];
#pragma unroll
  for (int i = 0; i < 3; ++i) {
    int pos = posbase + i * 16 + l15;
    int y = pos / 24, x = pos % 24;
    lr[i] = y - pchunk * 8;      // 0..7
    lx[i] = x;
  }
  int ibn[4];
#pragma unroll
  for (int nt = 0; nt < 4; ++nt) ibn[nt] = (nt * 16 + l15) * 64 + kg * 8;
  f32x4 acc[3][4];
#pragma unroll
  for (int i = 0; i < 3; ++i)
#pragma unroll
    for (int nt = 0; nt < 4; ++nt) acc[i][nt] = (f32x4){0.f, 0.f, 0.f, 0.f};

#pragma unroll 1
  for (int ks = 0; ks < 2; ++ks) {
    if (ks) __syncthreads();
    for (int e = t; e < 1040; e += 256) {     // 260 pos x 4 chunks of 8 shorts
      int p = e >> 2, s = e & 3;
      *(short8*)(slabh + p * 40 + s * 8) = *(const short8*)(gh + p * 64 + ks * 32 + s * 8);
      *(short8*)(slabl + p * 40 + s * 8) = *(const short8*)(gl + p * 64 + ks * 32 + s * 8);
    }
    __syncthreads();
    int ko = ks * 32;
#pragma unroll 3
    for (int tap = 0; tap < 9; ++tap) {
      int kh = tap / 3, kw = tap % 3;
      int wboff = tap * 4096 + ko;
      short8 Ah[3], Al[3], Bh[4], Bl[4];
#pragma unroll
      for (int i = 0; i < 3; ++i) {
        int p = (lr[i] + kh) * 26 + lx[i] + kw;    // 0..259
        int d = p * 40 + kg * 8;
        Ah[i] = *(const short8*)(slabh + d);
        Al[i] = *(const short8*)(slabl + d);
      }
#pragma unroll
      for (int nt = 0; nt < 4; ++nt) {
        Bh[nt] = *(const short8*)(whi + wboff + ibn[nt]);
        Bl[nt] = *(const short8*)(wlo + wboff + ibn[nt]);
      }
#pragma unroll
      for (int i = 0; i < 3; ++i)
#pragma unroll
        for (int nt = 0; nt < 4; ++nt) {
          acc[i][nt] = __builtin_amdgcn_mfma_f32_16x16x32_bf16(Ah[i], Bh[nt], acc[i][nt], 0, 0, 0);
          acc[i][nt] = __builtin_amdgcn_mfma_f32_16x16x32_bf16(Ah[i], Bl[nt], acc[i][nt], 0, 0, 0);
          acc[i][nt] = __builtin_amdgcn_mfma_f32_16x16x32_bf16(Al[i], Bh[nt], acc[i][nt], 0, 0, 0);
        }
    }
  }
  float bv[4];
#pragma unroll
  for (int nt = 0; nt < 4; ++nt) bv[nt] = bias[nt * 16 + l15];
  size_t ob = (size_t)b * KP;
#pragma unroll
  for (int i = 0; i < 3; ++i) {
#pragma unroll
    for (int r = 0; r < 4; ++r) {
      int pos = posbase + i * 16 + kg * 4 + r;
      size_t o = ob + (size_t)pos * 64 + l15;
#pragma unroll
      for (int np = 0; np < 2; ++np) {
        float v0 = acc[i][2 * np][r] + bv[2 * np];         v0 = v0 > 0.f ? v0 : 0.f;
        float v1 = acc[i][2 * np + 1][r] + bv[2 * np + 1]; v1 = v1 > 0.f ? v1 : 0.f;
        unsigned hp, lp;
        cvt2(v0, v1, hp, lp);
        bhi[o + (2 * np) * 16]     = (unsigned short)(hp & 0xffff);
        bhi[o + (2 * np + 1) * 16] = (unsigned short)(hp >> 16);
        blo[o + (2 * np) * 16]     = (unsigned short)(lp & 0xffff);
        blo[o + (2 * np + 1) * 16] = (unsigned short)(lp >> 16);
      }
    }
  }
}

// ---- prep_fc1: w1 feat-part permuted transpose (blocks <1152) + hist tail (>=1152) ----
// runs after conv loop (base planes alias the dead c1 region).
__global__ __launch_bounds__(256) void prep_fc1(const float* __restrict__ w,
    const float* __restrict__ hist, unsigned short* __restrict__ hi,
    unsigned short* __restrict__ lo, unsigned short* __restrict__ bhi,
    unsigned short* __restrict__ blo)
{
  __shared__ float tl[64][65];
  int bx = blockIdx.x;
  int t = threadIdx.x;
  if (bx < 1152) {
    int o = bx / 9;
    int p0 = (bx % 9) * 64;
    const float* src = w + (size_t)o * K1;
    for (int e = t; e < 4096; e += 256) {
      int c = e >> 6, p = e & 63;
      tl[p][c] = src[c * 576 + p0 + p];
    }
    __syncthreads();
    size_t dbase = (size_t)o * KP;
    for (int e = t; e < 4096; e += 256) {
      int p = e >> 6, c = e & 63;
      float x = tl[p][c];
      unsigned short h = f2bf(x);
      size_t d = dbase + (size_t)(p0 + p) * 64 + c;
      hi[d] = h; lo[d] = f2bf(x - bf2f(h));
    }
  } else {
    int j = (bx - 1152) * 256 + t;        // 0..24575
    if (j < 24576) {
      int b = j / 96, tt = j % 96;
      int k = FEAT + tt;
      float x = (k < K1) ? hist[b * HIST + tt] : 0.f;
      unsigned short h = f2bf(x);
      size_t o = (size_t)b * KP + k;
      bhi[o] = h; blo[o] = f2bf(x - bf2f(h));
    }
  }
}

// ---- fc1 MFMA bf16x3 split-K (round-22 config: 32 samples x 16 outs) ----
__global__ __launch_bounds__(256) void fc1_mfma(const unsigned short* __restrict__ bhi,
    const unsigned short* __restrict__ blo, const unsigned short* __restrict__ whi,
    const unsigned short* __restrict__ wlo, float* __restrict__ part)
{
  int w = threadIdx.x >> 6, lane = threadIdx.x & 63;
  int job = blockIdx.x * 4 + w;        // 0..63
  int mt2 = job & 7, nt = job >> 3;
  int ks = blockIdx.y;                 // 0..32
  int k0 = ks * 35 * 32;
  int l15 = lane & 15, kg = lane >> 4;
  int s0 = mt2 * 32 + l15;
  int o  = nt * 16 + l15;
  const unsigned short* pa0h = bhi + (size_t)s0 * KP + k0 + kg * 8;
  const unsigned short* pa1h = pa0h + (size_t)16 * KP;
  const unsigned short* pa0l = blo + (size_t)s0 * KP + k0 + kg * 8;
  const unsigned short* pa1l = pa0l + (size_t)16 * KP;
  const unsigned short* pbh  = whi + (size_t)o * KP + k0 + kg * 8;
  const unsigned short* pbl  = wlo + (size_t)o * KP + k0 + kg * 8;
  f32x4 acc0 = {0.f, 0.f, 0.f, 0.f}, acc1 = {0.f, 0.f, 0.f, 0.f};
#pragma unroll 1
  for (int i = 0; i < 35; ++i) {
    short8 a0h = *(const short8*)pa0h;
    short8 a1h = *(const short8*)pa1h;
    short8 a0l = *(const short8*)pa0l;
    short8 a1l = *(const short8*)pa1l;
    short8 bh  = *(const short8*)pbh;
    short8 bl  = *(const short8*)pbl;
    acc0 = __builtin_amdgcn_mfma_f32_16x16x32_bf16(a0h, bh, acc0, 0, 0, 0);
    acc1 = __builtin_amdgcn_mfma_f32_16x16x32_bf16(a1h, bh, acc1, 0, 0, 0);
    acc0 = __builtin_amdgcn_mfma_f32_16x16x32_bf16(a0h, bl, acc0, 0, 0, 0);
    acc1 = __builtin_amdgcn_mfma_f32_16x16x32_bf16(a1h, bl, acc1, 0, 0, 0);
    acc0 = __builtin_amdgcn_mfma_f32_16x16x32_bf16(a0l, bh, acc0, 0, 0, 0);
    acc1 = __builtin_amdgcn_mfma_f32_16x16x32_bf16(a1l, bh, acc1, 0, 0, 0);
    pa0h += 32; pa1h += 32; pa0l += 32; pa1l += 32; pbh += 32; pbl += 32;
  }
  float* pp0 = part + (((size_t)ks * 64 + job) * 2) * 256;
  float* pp1 = pp0 + 256;
#pragma unroll
  for (int r = 0; r < 4; ++r) {
    pp0[r * 64 + lane] = acc0[r];
    pp1[r * 64 + lane] = acc1[r];
  }
}

// ---------------- SNN simulation with fused split-K reduce ----------------
// t<128 computes h1[b][t] = sum_ks partb (same fixed order as the old fc1_reduce;
// index algebra for i = b*128 + t is identical) + b1[t].
__global__ __launch_bounds__(256) void snn_ker(const float* __restrict__ partb,
    const float* __restrict__ b1, const float* __restrict__ w2T,
    const float* __restrict__ b2p, const float* __restrict__ w3,
    const float* __restrict__ b3p, float* __restrict__ out)
{
  int b = blockIdx.x, t = threadIdx.x;
  __shared__ float spk1l[128];
  __shared__ float part[4][9];
  float h1v = 0.f;
  if (t < 128) {
    int mt2 = b >> 5, ti = (b >> 4) & 1, nt = t >> 4;
    int job = nt * 8 + mt2;
    int r = b & 15, c = t & 15;
    int off = (job * 2 + ti) * 256 + (r & 3) * 64 + ((r >> 2) << 4) + c;
    float sum = 0.f;
#pragma unroll 1
    for (int ks = 0; ks < 33; ++ks) sum += partb[(size_t)ks * 32768 + off];
    h1v = sum + b1[t];
  }
  float b2 = b2p[t];
  float w3r[9];
#pragma unroll
  for (int j = 0; j < 9; ++j) w3r[j] = w3[j * 256 + t];
  float mem1 = 0.f, syn1 = 0.f, mem2 = 0.f, syn2 = 0.f;
  float syn3[9], mem3[9], pot[9];
#pragma unroll
  for (int j = 0; j < 9; ++j) { syn3[j] = 0.f; mem3[j] = 0.f; pot[j] = 0.f; }

#pragma unroll 1
  for (int step = 0; step < 10; ++step) {
    if (t < 128) {
      syn1 = ALPHA * syn1 + h1v;
      mem1 = BETA * mem1 + syn1;
      float s = (mem1 > 1.0f) ? 1.f : 0.f;
      spk1l[t] = s;
      mem1 -= s;
    }
    __syncthreads();
    float h2 = b2;
#pragma unroll
    for (int i = 0; i < 128; ++i) {
      h2 += spk1l[i] * w2T[i * 256 + t];
    }
    syn2 = ALPHA * syn2 + h2;
    mem2 = BETA * mem2 + syn2;
    float s2 = (mem2 > 1.0f) ? 1.f : 0.f;
    mem2 -= s2;

    float v[9];
#pragma unroll
    for (int j = 0; j < 9; ++j) v[j] = s2 * w3r[j];
#pragma unroll
    for (int j = 0; j < 9; ++j) {
      v[j] += __shfl_down(v[j], 32);
      v[j] += __shfl_down(v[j], 16);
      v[j] += __shfl_down(v[j], 8);
      v[j] += __shfl_down(v[j], 4);
      v[j] += __shfl_down(v[j], 2);
      v[j] += __shfl_down(v[j], 1);
    }
    if ((t & 63) == 0) {
#pragma unroll
      for (int j = 0; j < 9; ++j) part[t >> 6][j] = v[j];
    }
    __syncthreads();
    if (t == 0) {
#pragma unroll
      for (int j = 0; j < 9; ++j) {
        float h3 = part[0][j] + part[1][j] + part[2][j] + part[3][j] + b3p[j];
        syn3[j] = ALPHA * syn3[j] + h3;
        mem3[j] = BETA * mem3[j] + syn3[j];
        pot[j] += mem3[j];
      }
    }
  }
  if (t == 0) {
#pragma unroll
    for (int j = 0; j < 9; ++j) out[b * 9 + j] = pot[j] / 10.0f;
  }
}

// ---------------- host ----------------
extern "C" void kernel_launch(void* const* d_in, const int* in_sizes, int n_in,
                              void* d_out, int out_size, void* d_ws, size_t ws_size,
                              hipStream_t stream)
{
  const float* state = (const float*)d_in[0];
  const float* hist  = (const float*)d_in[1];
  const float* c1w   = (const float*)d_in[2];
  const float* c1b   = (const float*)d_in[3];
  const float* c2w   = (const float*)d_in[4];
  const float* c2b   = (const float*)d_in[5];
  const float* c3w   = (const float*)d_in[6];
  const float* c3b   = (const float*)d_in[7];
  const float* f1w   = (const float*)d_in[8];
  const float* f1b   = (const float*)d_in[9];
  const float* f2w   = (const float*)d_in[10];
  const float* f2b   = (const float*)d_in[11];
  const float* f3w   = (const float*)d_in[12];
  const float* f3b   = (const float*)d_in[13];
  float* out = (float*)d_out;
  float* ws  = (float*)d_ws;

  // workspace (float offsets), peak 29,419,520 floats (117.7 MB):
  //   c1hi [0, 6,195,200) c1lo [6,195,200, 12,390,400)       (half-batch, reused per pass;
  //        region later reused as base_hi [0, 4,730,880) base_lo [4,730,880, 9,461,760))
  //   c2hi [12,390,400, 17,928,192) c2lo [17,928,192, 23,465,984)  (full batch)
  //   w1_hi [23,465,984, 25,831,424) w1_lo [25,831,424, 28,196,864)
  //   partb [28,196,864, 29,278,208)
  //   w1chi [29,278,208, 29,281,280) w1clo [29,281,280, 29,284,352)
  //   w2hi [29,284,352, 29,300,736) w2lo [29,300,736, 29,317,120)
  //   w3hi [29,317,120, 29,335,552) w3lo [29,335,552, 29,353,984)
  //   wT2 [29,353,984, 29,386,752)
  unsigned short* c1hi    = (unsigned short*)(ws);
  unsigned short* c1lo    = (unsigned short*)(ws + 6195200);
  unsigned short* base_hi = (unsigned short*)(ws);
  unsigned short* base_lo = (unsigned short*)(ws + 4730880);
  unsigned short* c2hi    = (unsigned short*)(ws + 12390400);
  unsigned short* c2lo    = (unsigned short*)(ws + 17928192);
  unsigned short* w1_hi   = (unsigned short*)(ws + 23465984);
  unsigned short* w1_lo   = (unsigned short*)(ws + 25831424);
  float* partb    = ws + 28196864;
  unsigned short* w1chi   = (unsigned short*)(ws + 29278208);
  unsigned short* w1clo   = (unsigned short*)(ws + 29281280);
  unsigned short* w2_hi   = (unsigned short*)(ws + 29284352);
  unsigned short* w2_lo   = (unsigned short*)(ws + 29300736);
  unsigned short* w3_hi   = (unsigned short*)(ws + 29317120);
  unsigned short* w3_lo   = (unsigned short*)(ws + 29335552);
  float* wT2      = ws + 29353984;

  // merged small preprocessing (w1c, w2, w3, fc2-transpose, w1 tail)
  convert_small<<<dim3(472), 256, 0, stream>>>(c1w, c2w, c3w, f1w, f2w,
                                               w1chi, w1clo, w2_hi, w2_lo,
                                               w3_hi, w3_lo, wT2, w1_hi, w1_lo);
  // half-batch conv1 -> conv2 passes (conv1 reads fp32 state directly)
  for (int p = 0; p < 2; ++p) {
    conv1_mfma<<<dim3(16, 128), 256, 0, stream>>>(state, w1chi, w1clo, c1b,
                                                  c1hi, c1lo, p * 128);
    conv2_mfma<<<dim3(4, 64), 256, 0, stream>>>(c1hi, c1lo, w2_hi, w2_lo, c2b,
                                                c2hi, c2lo, p * 128);
  }
  // c1 dead -> region reused for base planes; w1 permute + hist tail merged
  prep_fc1<<<dim3(1248), 256, 0, stream>>>(f1w, hist, w1_hi, w1_lo, base_hi, base_lo);
  conv3_mfma<<<dim3(3, 256), 256, 0, stream>>>(c2hi, c2lo, w3_hi, w3_lo, c3b,
                                               base_hi, base_lo);
  fc1_mfma<<<dim3(16, 33), 256, 0, stream>>>(base_hi, base_lo, w1_hi, w1_lo, partb);
  snn_ker<<<dim3(256), 256, 0, stream>>>(partb, f1b, wT2, f2b, f3w, f3b, out);
}